// Round 25
// baseline (59.346 us; speedup 1.0000x reference)
//
#include <hip/hip_runtime.h>
#include <hip/hip_bf16.h>

// BasicBlock9: B=16, CIN=CP=64, H=W=64, K1=3 (deform), K2=5, EPS=1e-5
// FINAL (R31/R32 config, confirmed best: 58.5 / 59.3 us vs R28-plateau
//   59.6 / 61.6 -- XCD alignment win is real).
//   Config: fp16 pipeline (packed v_pk_fma_f16 blend); role-split fused
//   (8 waves: role0 = offset conv + lane^32 shuffle exchange + deform
//   with per-ks register discipline; role1 = conv5; slot-major f32 acc
//   exchange overlaid on ldsx); single staging barrier; 2-row conv3;
//   vectorized prep; XCD producer-consumer alignment (prep XCD k writes
//   rows 8k..8k+7, fused/conv3 blocks for those rows run on XCD k).
//   Session: 161.1 (prior) -> 69.0 -> ~58.9 us. Fused remains
//   latency-bound (~17% MfmaUtil) -- structural floor, not HW roofline;
//   all remaining candidate deltas < +-2us run noise.
//   (R24 resubmit #3: repeated UnresponsiveContainer infra failures.)

#define EPSv 1e-5f
#define XP 68  // padded x stride: cols -2..65

typedef _Float16 f16x2 __attribute__((ext_vector_type(2)));
typedef _Float16 f16x8 __attribute__((ext_vector_type(8)));
typedef __attribute__((ext_vector_type(16))) float f32x16;

__device__ inline ushort f2h(float f) {
  _Float16 h = (_Float16)f;
  return *(ushort*)&h;
}

// ---------------- prep: transpose x -> padded xTp (f16) + fragment-major weights ----------------
__global__ __launch_bounds__(256) void prep_kernel(
    const float* __restrict__ x, const float* __restrict__ w3,
    const float* __restrict__ w2, const float* __restrict__ w1,
    const float* __restrict__ w_off,
    ushort* __restrict__ xTp, ushort* __restrict__ w3F,
    ushort* __restrict__ w2F, ushort* __restrict__ w1F,
    ushort* __restrict__ wofF) {
  __shared__ float tile[64][65];
  const int blk = blockIdx.x;
  if (blk < 1024) {
    // XCD-aligned mapping: xcd = blk%8 writes rows y in [8*xcd, 8*xcd+8)
    const int y = ((blk & 7) << 3) | ((blk >> 3) & 7);
    const int b = blk >> 6;
    // 1024 float4 loads, 4 per thread
    for (int i = threadIdx.x; i < 1024; i += 256) {
      int ci = i >> 4, xx4 = (i & 15) * 4;
      float4 v = *(const float4*)&x[(((size_t)b * 64 + ci) * 64 + y) * 64 + xx4];
      tile[ci][xx4 + 0] = v.x;
      tile[ci][xx4 + 1] = v.y;
      tile[ci][xx4 + 2] = v.z;
      tile[ci][xx4 + 3] = v.w;
    }
    __syncthreads();
    // 1024 ushort4 stores, 4 per thread (column reads stride-65: conflict-free)
    for (int i = threadIdx.x; i < 1024; i += 256) {
      int xx = i >> 4, cip4 = (i & 15) * 4;
      ushort4 o;
      o.x = f2h(tile[cip4 + 0][xx]);
      o.y = f2h(tile[cip4 + 1][xx]);
      o.z = f2h(tile[cip4 + 2][xx]);
      o.w = f2h(tile[cip4 + 3][xx]);
      *(ushort4*)&xTp[(((size_t)(b * 64 + y) * XP) + (xx + 2)) * 64 + cip4] = o;
    }
    // zero halo cols {0,1,66,67}
    if (threadIdx.x < 128) {
      int colid = threadIdx.x >> 5;
      int col = (colid & 1) + (colid >> 1) * 66;  // 0,1,66,67
      int cip = (threadIdx.x & 31) * 2;
      ushort2 z; z.x = 0; z.y = 0;
      *(ushort2*)&xTp[(((size_t)(b * 64 + y) * XP) + col) * 64 + cip] = z;
    }
    return;
  }
  int idx = (blk - 1024) * 256 + threadIdx.x;
  if (idx < 102400) {  // w3F
    int j = idx & 7, lane = (idx >> 3) & 63, ks = (idx >> 9) & 3;
    int half = (idx >> 11) & 1, kk = idx >> 12;
    int ln = lane & 31, kh = lane >> 5;
    int co = half * 32 + ln, ci = ks * 16 + kh * 8 + j;
    w3F[idx] = f2h(w3[(co * 64 + ci) * 25 + kk]);
    return;
  }
  idx -= 102400;
  if (idx < 36864) {  // w2F
    int j = idx & 7, lane = (idx >> 3) & 63, ks = (idx >> 9) & 3;
    int half = (idx >> 11) & 1, kk = idx >> 12;
    int ln = lane & 31, kh = lane >> 5;
    int co = half * 32 + ln, ci = ks * 16 + kh * 8 + j;
    w2F[idx] = f2h(w2[(co * 64 + ci) * 9 + kk]);
    return;
  }
  idx -= 36864;
  if (idx < 36864) {  // w1F
    int j = idx & 7, lane = (idx >> 3) & 63, ks = (idx >> 9) & 3;
    int half = (idx >> 11) & 1, kk = idx >> 12;
    int ln = lane & 31, kh = lane >> 5;
    int co = half * 32 + ln, ci = ks * 16 + kh * 8 + j;
    w1F[idx] = f2h(w1[(co * 64 + ci) * 9 + kk]);
    return;
  }
  idx -= 36864;
  if (idx < 18432) {  // wofF
    int j = idx & 7, lane = (idx >> 3) & 63, ks = (idx >> 9) & 3;
    int kk = idx >> 11;
    int ln = lane & 31, kh = lane >> 5;
    int ci = ks * 16 + kh * 8 + j;
    wofF[idx] = f2h(ln < 18 ? w_off[(ln * 64 + ci) * 9 + kk] : 0.f);
  }
}

// packed fp16 bilinear blend of 4 corner f16x8 frags -> f16x8 (v_pk_fma_f16)
__device__ __forceinline__ f16x8 blend4(f16x8 va, f16x8 vb, f16x8 vc, f16x8 vd,
                                        f16x2 w00, f16x2 w01, f16x2 w10, f16x2 w11) {
  const f16x2* a = (const f16x2*)&va;
  const f16x2* b = (const f16x2*)&vb;
  const f16x2* c = (const f16x2*)&vc;
  const f16x2* d = (const f16x2*)&vd;
  f16x8 f;
  f16x2* fo = (f16x2*)&f;
#pragma unroll
  for (int i = 0; i < 4; ++i)
    fo[i] = a[i] * w00 + b[i] * w01 + c[i] * w10 + d[i] * w11;
  return f;
}

// ---------------- fused: offset conv + deform + conv5 -> s1T ----------------
// Grid (32, 16), 512 thr = 8 waves: role = wv>>2, r = (wv>>1)&1, nt = wv&1.
// role0 = offset+deform (per-ks loop), role1 = conv5.
// bx -> bxl XCD swizzle: block for y0 runs on XCD y0>>3 (matches prep writer).
__global__ __launch_bounds__(512, 4) void fused_kernel(
    const ushort* __restrict__ xTp, const ushort* __restrict__ wofF,
    const float* __restrict__ b_off, const ushort* __restrict__ w1F,
    const ushort* __restrict__ w3F,
    const float* __restrict__ g1, const float* __restrict__ b1,
    const float* __restrict__ m1, const float* __restrict__ v1,
    const float* __restrict__ g3, const float* __restrict__ b3,
    const float* __restrict__ m3, const float* __restrict__ v3,
    ushort* __restrict__ s1T) {
  __shared__ __align__(16) uint4 ldsx[6 * 68 * 8];  // 52224 B swizzled tile (exchange overlay: 32768 B)
  __shared__ float bn1s[64], bn1b[64], bn3s[64], bn3b[64];  // 1024 B

  const int tid = threadIdx.x;
  const int wv = tid >> 6, lane = tid & 63;
  const int ln = lane & 31, kh = lane >> 5;
  const int role = wv >> 2, r = (wv >> 1) & 1, nt = wv & 1;
  const int bxl = ((blockIdx.x & 7) << 2) | (blockIdx.x >> 3);  // XCD swizzle
  const int y0 = bxl * 2, b = blockIdx.y;
  const int y = y0 + r, px = nt * 32 + ln;
  const uint4* xT4 = (const uint4*)xTp;
  const ushort* xb = xTp + (size_t)b * 64 * XP * 64;
  const bool interior = (y0 >= 2 && y0 <= 60);  // block-uniform

  if (tid < 64) {
    float s = g1[tid] * rsqrtf(v1[tid] + EPSv);
    bn1s[tid] = s; bn1b[tid] = b1[tid] - m1[tid] * s;
    float s3 = g3[tid] * rsqrtf(v3[tid] + EPSv);
    bn3s[tid] = s3; bn3b[tid] = b3[tid] - m3[tid] * s3;
  }
  // stage rows y0-2..y0+3 (clamped), all 68 padded cols: no bounds branch
  for (int i = tid; i < 6 * 68 * 8; i += 512) {
    int tr = i / (68 * 8), rem = i % (68 * 8);
    int col = rem >> 3, c = rem & 7;
    int ysrc = min(max(y0 - 2 + tr, 0), 63);
    uint4 v = xT4[((size_t)((b * 64 + ysrc) * XP + col)) * 8 + c];
    ldsx[(tr * 68 + col) * 8 + (c ^ (col & 7))] = v;
  }
  __syncthreads();  // B1: tile staged

  // accKeep = my co-half output I keep (role0: deform co0-31; role1: conv5 co32-63)
  // accGive = the co-half I hand to my partner wave at the exchange.
  f32x16 accKeep, accGive;
#pragma unroll
  for (int j = 0; j < 16; ++j) { accKeep[j] = 0.f; accGive[j] = 0.f; }

  if (role == 0) {
    // ======== phase A: offset conv 3x3 from LDS (full cin) ========
    f32x16 acco;
#pragma unroll
    for (int j = 0; j < 16; ++j) acco[j] = 0.f;
    if (interior) {
#pragma unroll
      for (int kk = 0; kk < 9; ++kk) {
        const int ky = kk / 3, kx = kk % 3;
        const int tr = r + ky + 1;
        const int col = px + kx + 1;
#pragma unroll
        for (int ks = 0; ks < 4; ++ks) {
          int c = ks * 2 + kh;
          f16x8 af = *(const f16x8*)&wofF[(size_t)((kk * 4 + ks) * 64 + lane) * 8];
          f16x8 bf = *(const f16x8*)&ldsx[(tr * 68 + col) * 8 + (c ^ (col & 7))];
          acco = __builtin_amdgcn_mfma_f32_32x32x16_f16(af, bf, acco, 0, 0, 0);
        }
      }
    } else {
#pragma unroll
      for (int kk = 0; kk < 9; ++kk) {
        const int ky = kk / 3, kx = kk % 3;
        const int yy = y - 1 + ky;
        if (yy >= 0 && yy <= 63) {  // wave-uniform
          const int tr = yy - (y0 - 2);
          const int col = px + kx + 1;
#pragma unroll
          for (int ks = 0; ks < 4; ++ks) {
            int c = ks * 2 + kh;
            f16x8 af = *(const f16x8*)&wofF[(size_t)((kk * 4 + ks) * 64 + lane) * 8];
            f16x8 bf = *(const f16x8*)&ldsx[(tr * 68 + col) * 8 + (c ^ (col & 7))];
            acco = __builtin_amdgcn_mfma_f32_32x32x16_f16(af, bf, acco, 0, 0, 0);
          }
        }
      }
    }
    // offset exchange via lane^32 shuffle: co c -> reg (c&3)+4*(c>>3), src kh (c>>2)&1
    float oth[10];
#pragma unroll
    for (int t = 0; t < 10; ++t) oth[t] = __shfl_xor(acco[t], 32);
    float dyv[9], dxv[9];
#pragma unroll
    for (int kk = 0; kk < 9; ++kk) {
      const int cY = 2 * kk, cX = 2 * kk + 1;
      const int rY = (cY & 3) + 4 * (cY >> 3);
      const int rX = (cX & 3) + 4 * (cX >> 3);
      const int sY = (cY >> 2) & 1, sX = (cX >> 2) & 1;
      float vy = (sY == kh) ? acco[rY] : oth[rY];
      float vx = (sX == kh) ? acco[rX] : oth[rX];
      dyv[kk] = vy + b_off[cY];
      dxv[kk] = vx + b_off[cX];
    }
    bool fast = true;
#pragma unroll
    for (int kk = 0; kk < 9; ++kk) {
      int iy0 = (int)floorf((float)(y - 1 + kk / 3) + dyv[kk]);
      int iy1 = iy0 + 1;
      bool ok0 = (iy0 < 0) || (iy0 > 63) || (iy0 >= y0 - 2 && iy0 <= y0 + 3);
      bool ok1 = (iy1 < 0) || (iy1 > 63) || (iy1 >= y0 - 2 && iy1 <= y0 + 3);
      fast = fast && ok0 && ok1;
    }

    // ======== phase B: deformable conv 3x3 (per-ks register discipline) ========
    if (__ballot(!fast) == 0ull) {
      // branch-free fast loop (whole wave in-tile); one ks-slice live at a time
#pragma unroll
      for (int kk = 0; kk < 9; ++kk) {
        const int ky = kk / 3, kx = kk % 3;
        float ys = (float)(y - 1 + ky) + dyv[kk];
        float xs = (float)(px - 1 + kx) + dxv[kk];
        float y0f = floorf(ys), x0f = floorf(xs);
        float wy1 = ys - y0f, wx1 = xs - x0f;
        float wy0 = 1.f - wy1, wx0 = 1.f - wx1;
        int iy0 = (int)y0f, ix0 = (int)x0f;
        int iy1 = iy0 + 1, ix1 = ix0 + 1;
        float vy0 = (iy0 >= 0 && iy0 <= 63) ? 1.f : 0.f;
        float vy1 = (iy1 >= 0 && iy1 <= 63) ? 1.f : 0.f;
        float vx0 = (ix0 >= 0 && ix0 <= 63) ? 1.f : 0.f;
        float vx1 = (ix1 >= 0 && ix1 <= 63) ? 1.f : 0.f;
        int x0c = min(max(ix0, 0), 63), x1c = min(max(ix1, 0), 63);
        float w00 = wy0 * wx0 * vy0 * vx0;
        float w01 = wy0 * wx1 * vy0 * vx1;
        float w10 = wy1 * wx0 * vy1 * vx0;
        float w11 = wy1 * wx1 * vy1 * vx1;
        int tr0 = min(max(iy0 - (y0 - 2), 0), 5);
        int tr1 = min(max(iy1 - (y0 - 2), 0), 5);
        int c0 = x0c + 2, c1 = x1c + 2;
        f16x2 w00v = {(_Float16)w00, (_Float16)w00};
        f16x2 w01v = {(_Float16)w01, (_Float16)w01};
        f16x2 w10v = {(_Float16)w10, (_Float16)w10};
        f16x2 w11v = {(_Float16)w11, (_Float16)w11};
#pragma unroll
        for (int ks = 0; ks < 4; ++ks) {
          int c = ks * 2 + kh;
          f16x8 va = *(const f16x8*)&ldsx[(tr0 * 68 + c0) * 8 + (c ^ (c0 & 7))];
          f16x8 vb = *(const f16x8*)&ldsx[(tr0 * 68 + c1) * 8 + (c ^ (c1 & 7))];
          f16x8 vc = *(const f16x8*)&ldsx[(tr1 * 68 + c0) * 8 + (c ^ (c0 & 7))];
          f16x8 vd = *(const f16x8*)&ldsx[(tr1 * 68 + c1) * 8 + (c ^ (c1 & 7))];
          f16x8 f = blend4(va, vb, vc, vd, w00v, w01v, w10v, w11v);
          f16x8 a0 = *(const f16x8*)&w1F[(size_t)(((kk * 2 + 0) * 4 + ks) * 64 + lane) * 8];
          f16x8 a1 = *(const f16x8*)&w1F[(size_t)(((kk * 2 + 1) * 4 + ks) * 64 + lane) * 8];
          accKeep = __builtin_amdgcn_mfma_f32_32x32x16_f16(a0, f, accKeep, 0, 0, 0);
          accGive = __builtin_amdgcn_mfma_f32_32x32x16_f16(a1, f, accGive, 0, 0, 0);
        }
      }
    } else {
      // mixed loop (rare: some lane needs global gather); per-ks frag
#pragma unroll
      for (int kk = 0; kk < 9; ++kk) {
        const int ky = kk / 3, kx = kk % 3;
        float ys = (float)(y - 1 + ky) + dyv[kk];
        float xs = (float)(px - 1 + kx) + dxv[kk];
        float y0f = floorf(ys), x0f = floorf(xs);
        float wy1 = ys - y0f, wx1 = xs - x0f;
        float wy0 = 1.f - wy1, wx0 = 1.f - wx1;
        int iy0 = (int)y0f, ix0 = (int)x0f;
        int iy1 = iy0 + 1, ix1 = ix0 + 1;
        float vy0 = (iy0 >= 0 && iy0 <= 63) ? 1.f : 0.f;
        float vy1 = (iy1 >= 0 && iy1 <= 63) ? 1.f : 0.f;
        float vx0 = (ix0 >= 0 && ix0 <= 63) ? 1.f : 0.f;
        float vx1 = (ix1 >= 0 && ix1 <= 63) ? 1.f : 0.f;
        int x0c = min(max(ix0, 0), 63), x1c = min(max(ix1, 0), 63);
        int y0c = min(max(iy0, 0), 63), y1c = min(max(iy1, 0), 63);
        float w00 = wy0 * wx0 * vy0 * vx0;
        float w01 = wy0 * wx1 * vy0 * vx1;
        float w10 = wy1 * wx0 * vy1 * vx0;
        float w11 = wy1 * wx1 * vy1 * vx1;
        int tr0 = min(max(iy0 - (y0 - 2), 0), 5);
        int tr1 = min(max(iy1 - (y0 - 2), 0), 5);
        int c0 = x0c + 2, c1 = x1c + 2;
        f16x2 w00v = {(_Float16)w00, (_Float16)w00};
        f16x2 w01v = {(_Float16)w01, (_Float16)w01};
        f16x2 w10v = {(_Float16)w10, (_Float16)w10};
        f16x2 w11v = {(_Float16)w11, (_Float16)w11};
        const ushort* p00 = xb + ((size_t)(y0c * XP + x0c + 2)) * 64 + kh * 8;
        const ushort* p01 = xb + ((size_t)(y0c * XP + x1c + 2)) * 64 + kh * 8;
        const ushort* p10 = xb + ((size_t)(y1c * XP + x0c + 2)) * 64 + kh * 8;
        const ushort* p11 = xb + ((size_t)(y1c * XP + x1c + 2)) * 64 + kh * 8;
#pragma unroll
        for (int ks = 0; ks < 4; ++ks) {
          int c = ks * 2 + kh;
          f16x8 f;
          if (fast) {
            f16x8 va = *(const f16x8*)&ldsx[(tr0 * 68 + c0) * 8 + (c ^ (c0 & 7))];
            f16x8 vb = *(const f16x8*)&ldsx[(tr0 * 68 + c1) * 8 + (c ^ (c1 & 7))];
            f16x8 vc = *(const f16x8*)&ldsx[(tr1 * 68 + c0) * 8 + (c ^ (c0 & 7))];
            f16x8 vd = *(const f16x8*)&ldsx[(tr1 * 68 + c1) * 8 + (c ^ (c1 & 7))];
            f = blend4(va, vb, vc, vd, w00v, w01v, w10v, w11v);
          } else {
            f16x8 va = *(const f16x8*)(p00 + ks * 16);
            f16x8 vb = *(const f16x8*)(p01 + ks * 16);
            f16x8 vc = *(const f16x8*)(p10 + ks * 16);
            f16x8 vd = *(const f16x8*)(p11 + ks * 16);
            f = blend4(va, vb, vc, vd, w00v, w01v, w10v, w11v);
          }
          f16x8 a0 = *(const f16x8*)&w1F[(size_t)(((kk * 2 + 0) * 4 + ks) * 64 + lane) * 8];
          f16x8 a1 = *(const f16x8*)&w1F[(size_t)(((kk * 2 + 1) * 4 + ks) * 64 + lane) * 8];
          accKeep = __builtin_amdgcn_mfma_f32_32x32x16_f16(a0, f, accKeep, 0, 0, 0);
          accGive = __builtin_amdgcn_mfma_f32_32x32x16_f16(a1, f, accGive, 0, 0, 0);
        }
      }
    }
  } else {
    // ======== conv 5x5 from LDS (full cin) ========
    // accGive = co 0-31 (goes to role0 partner), accKeep = co 32-63
    if (interior) {
#pragma unroll
      for (int kk = 0; kk < 25; ++kk) {
        const int ky = kk / 5, kx = kk % 5;
        const int tr = r + ky;
        const int col = px + kx;
        f16x8 a0[4], a1[4], bfv[4];
#pragma unroll
        for (int ks = 0; ks < 4; ++ks) {
          a0[ks] = *(const f16x8*)&w3F[(size_t)(((kk * 2 + 0) * 4 + ks) * 64 + lane) * 8];
          a1[ks] = *(const f16x8*)&w3F[(size_t)(((kk * 2 + 1) * 4 + ks) * 64 + lane) * 8];
        }
#pragma unroll
        for (int ks = 0; ks < 4; ++ks) {
          int c = ks * 2 + kh;
          bfv[ks] = *(const f16x8*)&ldsx[(tr * 68 + col) * 8 + (c ^ (col & 7))];
        }
#pragma unroll
        for (int ks = 0; ks < 4; ++ks) {
          accGive = __builtin_amdgcn_mfma_f32_32x32x16_f16(a0[ks], bfv[ks], accGive, 0, 0, 0);
          accKeep = __builtin_amdgcn_mfma_f32_32x32x16_f16(a1[ks], bfv[ks], accKeep, 0, 0, 0);
        }
      }
    } else {
#pragma unroll
      for (int kk = 0; kk < 25; ++kk) {
        const int ky = kk / 5, kx = kk % 5;
        const int yy = y - 2 + ky;
        if (yy >= 0 && yy <= 63) {  // wave-uniform
          const int tr = r + ky;
          const int col = px + kx;
#pragma unroll
          for (int ks = 0; ks < 4; ++ks) {
            int c = ks * 2 + kh;
            f16x8 bf = *(const f16x8*)&ldsx[(tr * 68 + col) * 8 + (c ^ (col & 7))];
            f16x8 a0 = *(const f16x8*)&w3F[(size_t)(((kk * 2 + 0) * 4 + ks) * 64 + lane) * 8];
            f16x8 a1 = *(const f16x8*)&w3F[(size_t)(((kk * 2 + 1) * 4 + ks) * 64 + lane) * 8];
            accGive = __builtin_amdgcn_mfma_f32_32x32x16_f16(a0, bf, accGive, 0, 0, 0);
            accKeep = __builtin_amdgcn_mfma_f32_32x32x16_f16(a1, bf, accKeep, 0, 0, 0);
          }
        }
      }
    }
  }

  // ---------- exchange: swap co-half partials between role pair ----------
  // Slot-major overlay on ldsx: float4 sp[(pair*8 + slot)*64 + lane],
  // pair = wv&3 (role0 wave wv pairs role1 wave wv+4). 32 slots x 64
  // lanes x 16 B = 32768 B < 52224 B (bn arrays untouched). Per-slot
  // lane-consecutive float4s -> conflict-free.
  __syncthreads();  // B2 (all ldsx tile reads complete; overlay safe)
  {
    float4* sp = (float4*)ldsx;
    const int base = (wv & 3) * 8;
    union U { f32x16 v; float4 q[4]; };
    U give, got;
    give.v = accGive;
    const int wbase = base + role * 4;
#pragma unroll
    for (int j = 0; j < 4; ++j) sp[(size_t)(wbase + j) * 64 + lane] = give.q[j];
    __syncthreads();  // B3
    const int rbase = base + 4 - role * 4;
#pragma unroll
    for (int j = 0; j < 4; ++j) got.q[j] = sp[(size_t)(rbase + j) * 64 + lane];

    // role0: vd from accKeep (deform co0-31), v5 from got (conv5 co0-31)
    // role1: vd from got (deform co32-63), v5 from accKeep (conv5 co32-63)
    f32x16 vdacc = (role == 0) ? accKeep : got.v;
    f32x16 v5acc = (role == 0) ? got.v : accKeep;
    ushort* op = s1T + ((size_t)((b * 64 + y) * 64 + px)) * 64 + role * 32;
#pragma unroll
    for (int q = 0; q < 4; ++q) {
      int co0 = role * 32 + 8 * q + 4 * kh;
      float vv[4];
#pragma unroll
      for (int rr = 0; rr < 4; ++rr) {
        int co = co0 + rr;
        float vd = vdacc[q * 4 + rr] * bn1s[co] + bn1b[co];
        vd = vd > 0.f ? vd : 0.f;
        float v5 = v5acc[q * 4 + rr] * bn3s[co] + bn3b[co];
        v5 = v5 > 0.f ? v5 : 0.f;
        vv[rr] = vd + v5;
      }
      ushort4 st;
      st.x = f2h(vv[0]); st.y = f2h(vv[1]); st.z = f2h(vv[2]); st.w = f2h(vv[3]);
      *(ushort4*)(op + 8 * q + 4 * kh) = st;
    }
  }
}

// ---------------- conv3x3 on s1T + BN2 + residual + ReLU -> out ----------------
// 2-row blocks. Grid (32,16)=512, 512 thr = 8 waves (r=wv>>2,
// mh=(wv>>1)&1, nt=wv&1). Same bxl XCD swizzle as fused (reads s1T rows
// written by the same-XCD fused block).
__global__ __launch_bounds__(512, 4) void conv3_mfma_kernel(
    const ushort* __restrict__ s1T, const ushort* __restrict__ w2F,
    const float* __restrict__ g2, const float* __restrict__ b2,
    const float* __restrict__ m2, const float* __restrict__ v2,
    const float* __restrict__ x, float* __restrict__ out) {
  __shared__ __align__(16) uint4 Bt[4 * 66 * 8];  // 33792 B swizzled
  __shared__ float sc[64], bi[64];
  const int tid = threadIdx.x;
  if (tid < 64) {
    float s = g2[tid] * rsqrtf(v2[tid] + EPSv);
    sc[tid] = s;
    bi[tid] = b2[tid] - m2[tid] * s;
  }
  const int bxl = ((blockIdx.x & 7) << 2) | (blockIdx.x >> 3);  // XCD swizzle
  const int y0 = bxl * 2, b = blockIdx.y;
  const int wv = tid >> 6, lane = tid & 63;
  const int ln = lane & 31, kh = lane >> 5;
  const int r = wv >> 2, mh = (wv >> 1) & 1, nt = wv & 1;
  const int y = y0 + r;
  const int px = nt * 32 + ln;
  const uint4* s1T4 = (const uint4*)s1T;

  // stage rows y0-1..y0+2 (OOB rows zero), cols 0..65 = x cols -1..64 (OOB zero)
  for (int i = tid; i < 4 * 66 * 8; i += 512) {
    int tr = i / (66 * 8), rem = i % (66 * 8);
    int col = rem >> 3, c = rem & 7;
    int yy = y0 - 1 + tr, xcol = col - 1;
    uint4 v = make_uint4(0, 0, 0, 0);
    if (yy >= 0 && yy <= 63 && xcol >= 0 && xcol <= 63)
      v = s1T4[((size_t)((b * 64 + yy) * 64 + xcol)) * 8 + c];
    Bt[(tr * 66 + col) * 8 + (c ^ (col & 7))] = v;
  }
  __syncthreads();

  f32x16 acc;
#pragma unroll
  for (int j = 0; j < 16; ++j) acc[j] = 0.f;

#pragma unroll
  for (int kk = 0; kk < 9; ++kk) {
    const int ky = kk / 3, kx = kk % 3;
    const int col = px + kx;
    f16x8 af[4], bfr[4];
#pragma unroll
    for (int ccb = 0; ccb < 4; ++ccb)
      af[ccb] = *(const f16x8*)&w2F[(size_t)(((kk * 2 + mh) * 4 + ccb) * 64 + lane) * 8];
#pragma unroll
    for (int ccb = 0; ccb < 4; ++ccb) {
      int c = ccb * 2 + kh;
      bfr[ccb] = *(const f16x8*)&Bt[((r + ky) * 66 + col) * 8 + (c ^ (col & 7))];
    }
#pragma unroll
    for (int ccb = 0; ccb < 4; ++ccb)
      acc = __builtin_amdgcn_mfma_f32_32x32x16_f16(af[ccb], bfr[ccb], acc, 0, 0, 0);
  }
#pragma unroll
  for (int reg = 0; reg < 16; ++reg) {
    int co = (reg & 3) + 8 * (reg >> 2) + 4 * kh + mh * 32;
    size_t o = (((size_t)b * 64 + co) * 64 + y) * 64 + px;
    float v = acc[reg] * sc[co] + bi[co] + x[o];
    out[o] = v > 0.f ? v : 0.f;
  }
}

extern "C" void kernel_launch(void* const* d_in, const int* in_sizes, int n_in,
                              void* d_out, int out_size, void* d_ws, size_t ws_size,
                              hipStream_t stream) {
  const float* x     = (const float*)d_in[0];
  const float* w_off = (const float*)d_in[1];
  const float* b_off = (const float*)d_in[2];
  const float* w1    = (const float*)d_in[3];
  const float* g1    = (const float*)d_in[4];
  const float* b1    = (const float*)d_in[5];
  const float* m1    = (const float*)d_in[6];
  const float* v1    = (const float*)d_in[7];
  const float* w3    = (const float*)d_in[8];
  const float* g3    = (const float*)d_in[9];
  const float* b3    = (const float*)d_in[10];
  const float* m3    = (const float*)d_in[11];
  const float* v3    = (const float*)d_in[12];
  const float* w2    = (const float*)d_in[13];
  const float* g2    = (const float*)d_in[14];
  const float* b2    = (const float*)d_in[15];
  const float* m2    = (const float*)d_in[16];
  const float* v2    = (const float*)d_in[17];
  float* out = (float*)d_out;

  ushort* xTp  = (ushort*)d_ws;                        // 16*64*68*64 = 8.9 MB
  ushort* s1T  = xTp + (size_t)16 * 64 * XP * 64;      // 8.39 MB
  ushort* w3F  = s1T + (size_t)16 * 64 * 64 * 64;      // 102400
  ushort* w2F  = w3F + 102400;                         // 36864
  ushort* w1F  = w2F + 36864;                          // 36864
  ushort* wofF = w1F + 36864;                          // 18432

  prep_kernel<<<dim3(1024 + 760), dim3(256), 0, stream>>>(x, w3, w2, w1, w_off,
                                                          xTp, w3F, w2F, w1F, wofF);
  fused_kernel<<<dim3(32, 16), dim3(512), 0, stream>>>(xTp, wofF, b_off, w1F, w3F,
                                                       g1, b1, m1, v1, g3, b3, m3, v3,
                                                       s1T);
  conv3_mfma_kernel<<<dim3(32, 16), dim3(512), 0, stream>>>(s1T, w2F, g2, b2, m2, v2,
                                                            x, out);
}

// Round 26
// 58.659 us; speedup vs baseline: 1.0117x; 1.0117x over previous
//
#include <hip/hip_runtime.h>
#include <hip/hip_bf16.h>

// BasicBlock9: B=16, CIN=CP=64, H=W=64, K1=3 (deform), K2=5, EPS=1e-5
// FINAL (confirmed x3: 58.5 / 59.3 / 59.3 us; R28-plateau was 59.6/61.6).
//   Config: fp16 pipeline (packed v_pk_fma_f16 blend); role-split fused
//   (8 waves: role0 = offset conv + lane^32 shuffle exchange + deform
//   with per-ks register discipline; role1 = conv5; slot-major f32 acc
//   exchange overlaid on ldsx); single staging barrier; 2-row conv3;
//   vectorized prep; XCD producer-consumer alignment (prep XCD k writes
//   rows 8k..8k+7, fused/conv3 blocks for those rows run on XCD k).
//   Session: 161.1 (prior) -> 69.0 -> ~59 us. Fused is latency-bound
//   (~17% MfmaUtil) -- structural floor, not HW roofline; all remaining
//   candidate deltas < +-2us run noise.

#define EPSv 1e-5f
#define XP 68  // padded x stride: cols -2..65

typedef _Float16 f16x2 __attribute__((ext_vector_type(2)));
typedef _Float16 f16x8 __attribute__((ext_vector_type(8)));
typedef __attribute__((ext_vector_type(16))) float f32x16;

__device__ inline ushort f2h(float f) {
  _Float16 h = (_Float16)f;
  return *(ushort*)&h;
}

// ---------------- prep: transpose x -> padded xTp (f16) + fragment-major weights ----------------
__global__ __launch_bounds__(256) void prep_kernel(
    const float* __restrict__ x, const float* __restrict__ w3,
    const float* __restrict__ w2, const float* __restrict__ w1,
    const float* __restrict__ w_off,
    ushort* __restrict__ xTp, ushort* __restrict__ w3F,
    ushort* __restrict__ w2F, ushort* __restrict__ w1F,
    ushort* __restrict__ wofF) {
  __shared__ float tile[64][65];
  const int blk = blockIdx.x;
  if (blk < 1024) {
    // XCD-aligned mapping: xcd = blk%8 writes rows y in [8*xcd, 8*xcd+8)
    const int y = ((blk & 7) << 3) | ((blk >> 3) & 7);
    const int b = blk >> 6;
    // 1024 float4 loads, 4 per thread
    for (int i = threadIdx.x; i < 1024; i += 256) {
      int ci = i >> 4, xx4 = (i & 15) * 4;
      float4 v = *(const float4*)&x[(((size_t)b * 64 + ci) * 64 + y) * 64 + xx4];
      tile[ci][xx4 + 0] = v.x;
      tile[ci][xx4 + 1] = v.y;
      tile[ci][xx4 + 2] = v.z;
      tile[ci][xx4 + 3] = v.w;
    }
    __syncthreads();
    // 1024 ushort4 stores, 4 per thread (column reads stride-65: conflict-free)
    for (int i = threadIdx.x; i < 1024; i += 256) {
      int xx = i >> 4, cip4 = (i & 15) * 4;
      ushort4 o;
      o.x = f2h(tile[cip4 + 0][xx]);
      o.y = f2h(tile[cip4 + 1][xx]);
      o.z = f2h(tile[cip4 + 2][xx]);
      o.w = f2h(tile[cip4 + 3][xx]);
      *(ushort4*)&xTp[(((size_t)(b * 64 + y) * XP) + (xx + 2)) * 64 + cip4] = o;
    }
    // zero halo cols {0,1,66,67}
    if (threadIdx.x < 128) {
      int colid = threadIdx.x >> 5;
      int col = (colid & 1) + (colid >> 1) * 66;  // 0,1,66,67
      int cip = (threadIdx.x & 31) * 2;
      ushort2 z; z.x = 0; z.y = 0;
      *(ushort2*)&xTp[(((size_t)(b * 64 + y) * XP) + col) * 64 + cip] = z;
    }
    return;
  }
  int idx = (blk - 1024) * 256 + threadIdx.x;
  if (idx < 102400) {  // w3F
    int j = idx & 7, lane = (idx >> 3) & 63, ks = (idx >> 9) & 3;
    int half = (idx >> 11) & 1, kk = idx >> 12;
    int ln = lane & 31, kh = lane >> 5;
    int co = half * 32 + ln, ci = ks * 16 + kh * 8 + j;
    w3F[idx] = f2h(w3[(co * 64 + ci) * 25 + kk]);
    return;
  }
  idx -= 102400;
  if (idx < 36864) {  // w2F
    int j = idx & 7, lane = (idx >> 3) & 63, ks = (idx >> 9) & 3;
    int half = (idx >> 11) & 1, kk = idx >> 12;
    int ln = lane & 31, kh = lane >> 5;
    int co = half * 32 + ln, ci = ks * 16 + kh * 8 + j;
    w2F[idx] = f2h(w2[(co * 64 + ci) * 9 + kk]);
    return;
  }
  idx -= 36864;
  if (idx < 36864) {  // w1F
    int j = idx & 7, lane = (idx >> 3) & 63, ks = (idx >> 9) & 3;
    int half = (idx >> 11) & 1, kk = idx >> 12;
    int ln = lane & 31, kh = lane >> 5;
    int co = half * 32 + ln, ci = ks * 16 + kh * 8 + j;
    w1F[idx] = f2h(w1[(co * 64 + ci) * 9 + kk]);
    return;
  }
  idx -= 36864;
  if (idx < 18432) {  // wofF
    int j = idx & 7, lane = (idx >> 3) & 63, ks = (idx >> 9) & 3;
    int kk = idx >> 11;
    int ln = lane & 31, kh = lane >> 5;
    int ci = ks * 16 + kh * 8 + j;
    wofF[idx] = f2h(ln < 18 ? w_off[(ln * 64 + ci) * 9 + kk] : 0.f);
  }
}

// packed fp16 bilinear blend of 4 corner f16x8 frags -> f16x8 (v_pk_fma_f16)
__device__ __forceinline__ f16x8 blend4(f16x8 va, f16x8 vb, f16x8 vc, f16x8 vd,
                                        f16x2 w00, f16x2 w01, f16x2 w10, f16x2 w11) {
  const f16x2* a = (const f16x2*)&va;
  const f16x2* b = (const f16x2*)&vb;
  const f16x2* c = (const f16x2*)&vc;
  const f16x2* d = (const f16x2*)&vd;
  f16x8 f;
  f16x2* fo = (f16x2*)&f;
#pragma unroll
  for (int i = 0; i < 4; ++i)
    fo[i] = a[i] * w00 + b[i] * w01 + c[i] * w10 + d[i] * w11;
  return f;
}

// ---------------- fused: offset conv + deform + conv5 -> s1T ----------------
// Grid (32, 16), 512 thr = 8 waves: role = wv>>2, r = (wv>>1)&1, nt = wv&1.
// role0 = offset+deform (per-ks loop), role1 = conv5.
// bx -> bxl XCD swizzle: block for y0 runs on XCD y0>>3 (matches prep writer).
__global__ __launch_bounds__(512, 4) void fused_kernel(
    const ushort* __restrict__ xTp, const ushort* __restrict__ wofF,
    const float* __restrict__ b_off, const ushort* __restrict__ w1F,
    const ushort* __restrict__ w3F,
    const float* __restrict__ g1, const float* __restrict__ b1,
    const float* __restrict__ m1, const float* __restrict__ v1,
    const float* __restrict__ g3, const float* __restrict__ b3,
    const float* __restrict__ m3, const float* __restrict__ v3,
    ushort* __restrict__ s1T) {
  __shared__ __align__(16) uint4 ldsx[6 * 68 * 8];  // 52224 B swizzled tile (exchange overlay: 32768 B)
  __shared__ float bn1s[64], bn1b[64], bn3s[64], bn3b[64];  // 1024 B

  const int tid = threadIdx.x;
  const int wv = tid >> 6, lane = tid & 63;
  const int ln = lane & 31, kh = lane >> 5;
  const int role = wv >> 2, r = (wv >> 1) & 1, nt = wv & 1;
  const int bxl = ((blockIdx.x & 7) << 2) | (blockIdx.x >> 3);  // XCD swizzle
  const int y0 = bxl * 2, b = blockIdx.y;
  const int y = y0 + r, px = nt * 32 + ln;
  const uint4* xT4 = (const uint4*)xTp;
  const ushort* xb = xTp + (size_t)b * 64 * XP * 64;
  const bool interior = (y0 >= 2 && y0 <= 60);  // block-uniform

  if (tid < 64) {
    float s = g1[tid] * rsqrtf(v1[tid] + EPSv);
    bn1s[tid] = s; bn1b[tid] = b1[tid] - m1[tid] * s;
    float s3 = g3[tid] * rsqrtf(v3[tid] + EPSv);
    bn3s[tid] = s3; bn3b[tid] = b3[tid] - m3[tid] * s3;
  }
  // stage rows y0-2..y0+3 (clamped), all 68 padded cols: no bounds branch
  for (int i = tid; i < 6 * 68 * 8; i += 512) {
    int tr = i / (68 * 8), rem = i % (68 * 8);
    int col = rem >> 3, c = rem & 7;
    int ysrc = min(max(y0 - 2 + tr, 0), 63);
    uint4 v = xT4[((size_t)((b * 64 + ysrc) * XP + col)) * 8 + c];
    ldsx[(tr * 68 + col) * 8 + (c ^ (col & 7))] = v;
  }
  __syncthreads();  // B1: tile staged

  // accKeep = my co-half output I keep (role0: deform co0-31; role1: conv5 co32-63)
  // accGive = the co-half I hand to my partner wave at the exchange.
  f32x16 accKeep, accGive;
#pragma unroll
  for (int j = 0; j < 16; ++j) { accKeep[j] = 0.f; accGive[j] = 0.f; }

  if (role == 0) {
    // ======== phase A: offset conv 3x3 from LDS (full cin) ========
    f32x16 acco;
#pragma unroll
    for (int j = 0; j < 16; ++j) acco[j] = 0.f;
    if (interior) {
#pragma unroll
      for (int kk = 0; kk < 9; ++kk) {
        const int ky = kk / 3, kx = kk % 3;
        const int tr = r + ky + 1;
        const int col = px + kx + 1;
#pragma unroll
        for (int ks = 0; ks < 4; ++ks) {
          int c = ks * 2 + kh;
          f16x8 af = *(const f16x8*)&wofF[(size_t)((kk * 4 + ks) * 64 + lane) * 8];
          f16x8 bf = *(const f16x8*)&ldsx[(tr * 68 + col) * 8 + (c ^ (col & 7))];
          acco = __builtin_amdgcn_mfma_f32_32x32x16_f16(af, bf, acco, 0, 0, 0);
        }
      }
    } else {
#pragma unroll
      for (int kk = 0; kk < 9; ++kk) {
        const int ky = kk / 3, kx = kk % 3;
        const int yy = y - 1 + ky;
        if (yy >= 0 && yy <= 63) {  // wave-uniform
          const int tr = yy - (y0 - 2);
          const int col = px + kx + 1;
#pragma unroll
          for (int ks = 0; ks < 4; ++ks) {
            int c = ks * 2 + kh;
            f16x8 af = *(const f16x8*)&wofF[(size_t)((kk * 4 + ks) * 64 + lane) * 8];
            f16x8 bf = *(const f16x8*)&ldsx[(tr * 68 + col) * 8 + (c ^ (col & 7))];
            acco = __builtin_amdgcn_mfma_f32_32x32x16_f16(af, bf, acco, 0, 0, 0);
          }
        }
      }
    }
    // offset exchange via lane^32 shuffle: co c -> reg (c&3)+4*(c>>3), src kh (c>>2)&1
    float oth[10];
#pragma unroll
    for (int t = 0; t < 10; ++t) oth[t] = __shfl_xor(acco[t], 32);
    float dyv[9], dxv[9];
#pragma unroll
    for (int kk = 0; kk < 9; ++kk) {
      const int cY = 2 * kk, cX = 2 * kk + 1;
      const int rY = (cY & 3) + 4 * (cY >> 3);
      const int rX = (cX & 3) + 4 * (cX >> 3);
      const int sY = (cY >> 2) & 1, sX = (cX >> 2) & 1;
      float vy = (sY == kh) ? acco[rY] : oth[rY];
      float vx = (sX == kh) ? acco[rX] : oth[rX];
      dyv[kk] = vy + b_off[cY];
      dxv[kk] = vx + b_off[cX];
    }
    bool fast = true;
#pragma unroll
    for (int kk = 0; kk < 9; ++kk) {
      int iy0 = (int)floorf((float)(y - 1 + kk / 3) + dyv[kk]);
      int iy1 = iy0 + 1;
      bool ok0 = (iy0 < 0) || (iy0 > 63) || (iy0 >= y0 - 2 && iy0 <= y0 + 3);
      bool ok1 = (iy1 < 0) || (iy1 > 63) || (iy1 >= y0 - 2 && iy1 <= y0 + 3);
      fast = fast && ok0 && ok1;
    }

    // ======== phase B: deformable conv 3x3 (per-ks register discipline) ========
    if (__ballot(!fast) == 0ull) {
      // branch-free fast loop (whole wave in-tile); one ks-slice live at a time
#pragma unroll
      for (int kk = 0; kk < 9; ++kk) {
        const int ky = kk / 3, kx = kk % 3;
        float ys = (float)(y - 1 + ky) + dyv[kk];
        float xs = (float)(px - 1 + kx) + dxv[kk];
        float y0f = floorf(ys), x0f = floorf(xs);
        float wy1 = ys - y0f, wx1 = xs - x0f;
        float wy0 = 1.f - wy1, wx0 = 1.f - wx1;
        int iy0 = (int)y0f, ix0 = (int)x0f;
        int iy1 = iy0 + 1, ix1 = ix0 + 1;
        float vy0 = (iy0 >= 0 && iy0 <= 63) ? 1.f : 0.f;
        float vy1 = (iy1 >= 0 && iy1 <= 63) ? 1.f : 0.f;
        float vx0 = (ix0 >= 0 && ix0 <= 63) ? 1.f : 0.f;
        float vx1 = (ix1 >= 0 && ix1 <= 63) ? 1.f : 0.f;
        int x0c = min(max(ix0, 0), 63), x1c = min(max(ix1, 0), 63);
        float w00 = wy0 * wx0 * vy0 * vx0;
        float w01 = wy0 * wx1 * vy0 * vx1;
        float w10 = wy1 * wx0 * vy1 * vx0;
        float w11 = wy1 * wx1 * vy1 * vx1;
        int tr0 = min(max(iy0 - (y0 - 2), 0), 5);
        int tr1 = min(max(iy1 - (y0 - 2), 0), 5);
        int c0 = x0c + 2, c1 = x1c + 2;
        f16x2 w00v = {(_Float16)w00, (_Float16)w00};
        f16x2 w01v = {(_Float16)w01, (_Float16)w01};
        f16x2 w10v = {(_Float16)w10, (_Float16)w10};
        f16x2 w11v = {(_Float16)w11, (_Float16)w11};
#pragma unroll
        for (int ks = 0; ks < 4; ++ks) {
          int c = ks * 2 + kh;
          f16x8 va = *(const f16x8*)&ldsx[(tr0 * 68 + c0) * 8 + (c ^ (c0 & 7))];
          f16x8 vb = *(const f16x8*)&ldsx[(tr0 * 68 + c1) * 8 + (c ^ (c1 & 7))];
          f16x8 vc = *(const f16x8*)&ldsx[(tr1 * 68 + c0) * 8 + (c ^ (c0 & 7))];
          f16x8 vd = *(const f16x8*)&ldsx[(tr1 * 68 + c1) * 8 + (c ^ (c1 & 7))];
          f16x8 f = blend4(va, vb, vc, vd, w00v, w01v, w10v, w11v);
          f16x8 a0 = *(const f16x8*)&w1F[(size_t)(((kk * 2 + 0) * 4 + ks) * 64 + lane) * 8];
          f16x8 a1 = *(const f16x8*)&w1F[(size_t)(((kk * 2 + 1) * 4 + ks) * 64 + lane) * 8];
          accKeep = __builtin_amdgcn_mfma_f32_32x32x16_f16(a0, f, accKeep, 0, 0, 0);
          accGive = __builtin_amdgcn_mfma_f32_32x32x16_f16(a1, f, accGive, 0, 0, 0);
        }
      }
    } else {
      // mixed loop (rare: some lane needs global gather); per-ks frag
#pragma unroll
      for (int kk = 0; kk < 9; ++kk) {
        const int ky = kk / 3, kx = kk % 3;
        float ys = (float)(y - 1 + ky) + dyv[kk];
        float xs = (float)(px - 1 + kx) + dxv[kk];
        float y0f = floorf(ys), x0f = floorf(xs);
        float wy1 = ys - y0f, wx1 = xs - x0f;
        float wy0 = 1.f - wy1, wx0 = 1.f - wx1;
        int iy0 = (int)y0f, ix0 = (int)x0f;
        int iy1 = iy0 + 1, ix1 = ix0 + 1;
        float vy0 = (iy0 >= 0 && iy0 <= 63) ? 1.f : 0.f;
        float vy1 = (iy1 >= 0 && iy1 <= 63) ? 1.f : 0.f;
        float vx0 = (ix0 >= 0 && ix0 <= 63) ? 1.f : 0.f;
        float vx1 = (ix1 >= 0 && ix1 <= 63) ? 1.f : 0.f;
        int x0c = min(max(ix0, 0), 63), x1c = min(max(ix1, 0), 63);
        int y0c = min(max(iy0, 0), 63), y1c = min(max(iy1, 0), 63);
        float w00 = wy0 * wx0 * vy0 * vx0;
        float w01 = wy0 * wx1 * vy0 * vx1;
        float w10 = wy1 * wx0 * vy1 * vx0;
        float w11 = wy1 * wx1 * vy1 * vx1;
        int tr0 = min(max(iy0 - (y0 - 2), 0), 5);
        int tr1 = min(max(iy1 - (y0 - 2), 0), 5);
        int c0 = x0c + 2, c1 = x1c + 2;
        f16x2 w00v = {(_Float16)w00, (_Float16)w00};
        f16x2 w01v = {(_Float16)w01, (_Float16)w01};
        f16x2 w10v = {(_Float16)w10, (_Float16)w10};
        f16x2 w11v = {(_Float16)w11, (_Float16)w11};
        const ushort* p00 = xb + ((size_t)(y0c * XP + x0c + 2)) * 64 + kh * 8;
        const ushort* p01 = xb + ((size_t)(y0c * XP + x1c + 2)) * 64 + kh * 8;
        const ushort* p10 = xb + ((size_t)(y1c * XP + x0c + 2)) * 64 + kh * 8;
        const ushort* p11 = xb + ((size_t)(y1c * XP + x1c + 2)) * 64 + kh * 8;
#pragma unroll
        for (int ks = 0; ks < 4; ++ks) {
          int c = ks * 2 + kh;
          f16x8 f;
          if (fast) {
            f16x8 va = *(const f16x8*)&ldsx[(tr0 * 68 + c0) * 8 + (c ^ (c0 & 7))];
            f16x8 vb = *(const f16x8*)&ldsx[(tr0 * 68 + c1) * 8 + (c ^ (c1 & 7))];
            f16x8 vc = *(const f16x8*)&ldsx[(tr1 * 68 + c0) * 8 + (c ^ (c0 & 7))];
            f16x8 vd = *(const f16x8*)&ldsx[(tr1 * 68 + c1) * 8 + (c ^ (c1 & 7))];
            f = blend4(va, vb, vc, vd, w00v, w01v, w10v, w11v);
          } else {
            f16x8 va = *(const f16x8*)(p00 + ks * 16);
            f16x8 vb = *(const f16x8*)(p01 + ks * 16);
            f16x8 vc = *(const f16x8*)(p10 + ks * 16);
            f16x8 vd = *(const f16x8*)(p11 + ks * 16);
            f = blend4(va, vb, vc, vd, w00v, w01v, w10v, w11v);
          }
          f16x8 a0 = *(const f16x8*)&w1F[(size_t)(((kk * 2 + 0) * 4 + ks) * 64 + lane) * 8];
          f16x8 a1 = *(const f16x8*)&w1F[(size_t)(((kk * 2 + 1) * 4 + ks) * 64 + lane) * 8];
          accKeep = __builtin_amdgcn_mfma_f32_32x32x16_f16(a0, f, accKeep, 0, 0, 0);
          accGive = __builtin_amdgcn_mfma_f32_32x32x16_f16(a1, f, accGive, 0, 0, 0);
        }
      }
    }
  } else {
    // ======== conv 5x5 from LDS (full cin) ========
    // accGive = co 0-31 (goes to role0 partner), accKeep = co 32-63
    if (interior) {
#pragma unroll
      for (int kk = 0; kk < 25; ++kk) {
        const int ky = kk / 5, kx = kk % 5;
        const int tr = r + ky;
        const int col = px + kx;
        f16x8 a0[4], a1[4], bfv[4];
#pragma unroll
        for (int ks = 0; ks < 4; ++ks) {
          a0[ks] = *(const f16x8*)&w3F[(size_t)(((kk * 2 + 0) * 4 + ks) * 64 + lane) * 8];
          a1[ks] = *(const f16x8*)&w3F[(size_t)(((kk * 2 + 1) * 4 + ks) * 64 + lane) * 8];
        }
#pragma unroll
        for (int ks = 0; ks < 4; ++ks) {
          int c = ks * 2 + kh;
          bfv[ks] = *(const f16x8*)&ldsx[(tr * 68 + col) * 8 + (c ^ (col & 7))];
        }
#pragma unroll
        for (int ks = 0; ks < 4; ++ks) {
          accGive = __builtin_amdgcn_mfma_f32_32x32x16_f16(a0[ks], bfv[ks], accGive, 0, 0, 0);
          accKeep = __builtin_amdgcn_mfma_f32_32x32x16_f16(a1[ks], bfv[ks], accKeep, 0, 0, 0);
        }
      }
    } else {
#pragma unroll
      for (int kk = 0; kk < 25; ++kk) {
        const int ky = kk / 5, kx = kk % 5;
        const int yy = y - 2 + ky;
        if (yy >= 0 && yy <= 63) {  // wave-uniform
          const int tr = r + ky;
          const int col = px + kx;
#pragma unroll
          for (int ks = 0; ks < 4; ++ks) {
            int c = ks * 2 + kh;
            f16x8 bf = *(const f16x8*)&ldsx[(tr * 68 + col) * 8 + (c ^ (col & 7))];
            f16x8 a0 = *(const f16x8*)&w3F[(size_t)(((kk * 2 + 0) * 4 + ks) * 64 + lane) * 8];
            f16x8 a1 = *(const f16x8*)&w3F[(size_t)(((kk * 2 + 1) * 4 + ks) * 64 + lane) * 8];
            accGive = __builtin_amdgcn_mfma_f32_32x32x16_f16(a0, bf, accGive, 0, 0, 0);
            accKeep = __builtin_amdgcn_mfma_f32_32x32x16_f16(a1, bf, accKeep, 0, 0, 0);
          }
        }
      }
    }
  }

  // ---------- exchange: swap co-half partials between role pair ----------
  // Slot-major overlay on ldsx: float4 sp[(pair*8 + slot)*64 + lane],
  // pair = wv&3 (role0 wave wv pairs role1 wave wv+4). 32 slots x 64
  // lanes x 16 B = 32768 B < 52224 B (bn arrays untouched). Per-slot
  // lane-consecutive float4s -> conflict-free.
  __syncthreads();  // B2 (all ldsx tile reads complete; overlay safe)
  {
    float4* sp = (float4*)ldsx;
    const int base = (wv & 3) * 8;
    union U { f32x16 v; float4 q[4]; };
    U give, got;
    give.v = accGive;
    const int wbase = base + role * 4;
#pragma unroll
    for (int j = 0; j < 4; ++j) sp[(size_t)(wbase + j) * 64 + lane] = give.q[j];
    __syncthreads();  // B3
    const int rbase = base + 4 - role * 4;
#pragma unroll
    for (int j = 0; j < 4; ++j) got.q[j] = sp[(size_t)(rbase + j) * 64 + lane];

    // role0: vd from accKeep (deform co0-31), v5 from got (conv5 co0-31)
    // role1: vd from got (deform co32-63), v5 from accKeep (conv5 co32-63)
    f32x16 vdacc = (role == 0) ? accKeep : got.v;
    f32x16 v5acc = (role == 0) ? got.v : accKeep;
    ushort* op = s1T + ((size_t)((b * 64 + y) * 64 + px)) * 64 + role * 32;
#pragma unroll
    for (int q = 0; q < 4; ++q) {
      int co0 = role * 32 + 8 * q + 4 * kh;
      float vv[4];
#pragma unroll
      for (int rr = 0; rr < 4; ++rr) {
        int co = co0 + rr;
        float vd = vdacc[q * 4 + rr] * bn1s[co] + bn1b[co];
        vd = vd > 0.f ? vd : 0.f;
        float v5 = v5acc[q * 4 + rr] * bn3s[co] + bn3b[co];
        v5 = v5 > 0.f ? v5 : 0.f;
        vv[rr] = vd + v5;
      }
      ushort4 st;
      st.x = f2h(vv[0]); st.y = f2h(vv[1]); st.z = f2h(vv[2]); st.w = f2h(vv[3]);
      *(ushort4*)(op + 8 * q + 4 * kh) = st;
    }
  }
}

// ---------------- conv3x3 on s1T + BN2 + residual + ReLU -> out ----------------
// 2-row blocks. Grid (32,16)=512, 512 thr = 8 waves (r=wv>>2,
// mh=(wv>>1)&1, nt=wv&1). Same bxl XCD swizzle as fused (reads s1T rows
// written by the same-XCD fused block).
__global__ __launch_bounds__(512, 4) void conv3_mfma_kernel(
    const ushort* __restrict__ s1T, const ushort* __restrict__ w2F,
    const float* __restrict__ g2, const float* __restrict__ b2,
    const float* __restrict__ m2, const float* __restrict__ v2,
    const float* __restrict__ x, float* __restrict__ out) {
  __shared__ __align__(16) uint4 Bt[4 * 66 * 8];  // 33792 B swizzled
  __shared__ float sc[64], bi[64];
  const int tid = threadIdx.x;
  if (tid < 64) {
    float s = g2[tid] * rsqrtf(v2[tid] + EPSv);
    sc[tid] = s;
    bi[tid] = b2[tid] - m2[tid] * s;
  }
  const int bxl = ((blockIdx.x & 7) << 2) | (blockIdx.x >> 3);  // XCD swizzle
  const int y0 = bxl * 2, b = blockIdx.y;
  const int wv = tid >> 6, lane = tid & 63;
  const int ln = lane & 31, kh = lane >> 5;
  const int r = wv >> 2, mh = (wv >> 1) & 1, nt = wv & 1;
  const int y = y0 + r;
  const int px = nt * 32 + ln;
  const uint4* s1T4 = (const uint4*)s1T;

  // stage rows y0-1..y0+2 (OOB rows zero), cols 0..65 = x cols -1..64 (OOB zero)
  for (int i = tid; i < 4 * 66 * 8; i += 512) {
    int tr = i / (66 * 8), rem = i % (66 * 8);
    int col = rem >> 3, c = rem & 7;
    int yy = y0 - 1 + tr, xcol = col - 1;
    uint4 v = make_uint4(0, 0, 0, 0);
    if (yy >= 0 && yy <= 63 && xcol >= 0 && xcol <= 63)
      v = s1T4[((size_t)((b * 64 + yy) * 64 + xcol)) * 8 + c];
    Bt[(tr * 66 + col) * 8 + (c ^ (col & 7))] = v;
  }
  __syncthreads();

  f32x16 acc;
#pragma unroll
  for (int j = 0; j < 16; ++j) acc[j] = 0.f;

#pragma unroll
  for (int kk = 0; kk < 9; ++kk) {
    const int ky = kk / 3, kx = kk % 3;
    const int col = px + kx;
    f16x8 af[4], bfr[4];
#pragma unroll
    for (int ccb = 0; ccb < 4; ++ccb)
      af[ccb] = *(const f16x8*)&w2F[(size_t)(((kk * 2 + mh) * 4 + ccb) * 64 + lane) * 8];
#pragma unroll
    for (int ccb = 0; ccb < 4; ++ccb) {
      int c = ccb * 2 + kh;
      bfr[ccb] = *(const f16x8*)&Bt[((r + ky) * 66 + col) * 8 + (c ^ (col & 7))];
    }
#pragma unroll
    for (int ccb = 0; ccb < 4; ++ccb)
      acc = __builtin_amdgcn_mfma_f32_32x32x16_f16(af[ccb], bfr[ccb], acc, 0, 0, 0);
  }
#pragma unroll
  for (int reg = 0; reg < 16; ++reg) {
    int co = (reg & 3) + 8 * (reg >> 2) + 4 * kh + mh * 32;
    size_t o = (((size_t)b * 64 + co) * 64 + y) * 64 + px;
    float v = acc[reg] * sc[co] + bi[co] + x[o];
    out[o] = v > 0.f ? v : 0.f;
  }
}

extern "C" void kernel_launch(void* const* d_in, const int* in_sizes, int n_in,
                              void* d_out, int out_size, void* d_ws, size_t ws_size,
                              hipStream_t stream) {
  const float* x     = (const float*)d_in[0];
  const float* w_off = (const float*)d_in[1];
  const float* b_off = (const float*)d_in[2];
  const float* w1    = (const float*)d_in[3];
  const float* g1    = (const float*)d_in[4];
  const float* b1    = (const float*)d_in[5];
  const float* m1    = (const float*)d_in[6];
  const float* v1    = (const float*)d_in[7];
  const float* w3    = (const float*)d_in[8];
  const float* g3    = (const float*)d_in[9];
  const float* b3    = (const float*)d_in[10];
  const float* m3    = (const float*)d_in[11];
  const float* v3    = (const float*)d_in[12];
  const float* w2    = (const float*)d_in[13];
  const float* g2    = (const float*)d_in[14];
  const float* b2    = (const float*)d_in[15];
  const float* m2    = (const float*)d_in[16];
  const float* v2    = (const float*)d_in[17];
  float* out = (float*)d_out;

  ushort* xTp  = (ushort*)d_ws;                        // 16*64*68*64 = 8.9 MB
  ushort* s1T  = xTp + (size_t)16 * 64 * XP * 64;      // 8.39 MB
  ushort* w3F  = s1T + (size_t)16 * 64 * 64 * 64;      // 102400
  ushort* w2F  = w3F + 102400;                         // 36864
  ushort* w1F  = w2F + 36864;                          // 36864
  ushort* wofF = w1F + 36864;                          // 18432

  prep_kernel<<<dim3(1024 + 760), dim3(256), 0, stream>>>(x, w3, w2, w1, w_off,
                                                          xTp, w3F, w2F, w1F, wofF);
  fused_kernel<<<dim3(32, 16), dim3(512), 0, stream>>>(xTp, wofF, b_off, w1F, w3F,
                                                       g1, b1, m1, v1, g3, b3, m3, v3,
                                                       s1T);
  conv3_mfma_kernel<<<dim3(32, 16), dim3(512), 0, stream>>>(s1T, w2F, g2, b2, m2, v2,
                                                            x, out);
}

// Round 27
// 57.864 us; speedup vs baseline: 1.0256x; 1.0137x over previous
//
#include <hip/hip_runtime.h>
#include <hip/hip_bf16.h>

// BasicBlock9: B=16, CIN=CP=64, H=W=64, K1=3 (deform), K2=5, EPS=1e-5
// FINAL (confirmed x4: 58.5 / 58.7 / 59.3 / 59.3 us).
//   Config: fp16 pipeline (packed v_pk_fma_f16 blend); role-split fused
//   (8 waves: role0 = offset conv + lane^32 shuffle exchange + deform
//   with per-ks register discipline; role1 = conv5; slot-major f32 acc
//   exchange overlaid on ldsx); single staging barrier; 2-row conv3;
//   vectorized prep; XCD producer-consumer alignment (prep XCD k writes
//   rows 8k..8k+7, fused/conv3 blocks for those rows run on XCD k).
//   Session: 161.1 (prior) -> 69.0 -> ~58.9 us. Fused is latency-bound
//   (~17% MfmaUtil) -- structural floor of the serial offset->deform
//   dataflow at 2 blocks/CU, not a HW roofline; all remaining candidate
//   deltas < +-2us run noise.

#define EPSv 1e-5f
#define XP 68  // padded x stride: cols -2..65

typedef _Float16 f16x2 __attribute__((ext_vector_type(2)));
typedef _Float16 f16x8 __attribute__((ext_vector_type(8)));
typedef __attribute__((ext_vector_type(16))) float f32x16;

__device__ inline ushort f2h(float f) {
  _Float16 h = (_Float16)f;
  return *(ushort*)&h;
}

// ---------------- prep: transpose x -> padded xTp (f16) + fragment-major weights ----------------
__global__ __launch_bounds__(256) void prep_kernel(
    const float* __restrict__ x, const float* __restrict__ w3,
    const float* __restrict__ w2, const float* __restrict__ w1,
    const float* __restrict__ w_off,
    ushort* __restrict__ xTp, ushort* __restrict__ w3F,
    ushort* __restrict__ w2F, ushort* __restrict__ w1F,
    ushort* __restrict__ wofF) {
  __shared__ float tile[64][65];
  const int blk = blockIdx.x;
  if (blk < 1024) {
    // XCD-aligned mapping: xcd = blk%8 writes rows y in [8*xcd, 8*xcd+8)
    const int y = ((blk & 7) << 3) | ((blk >> 3) & 7);
    const int b = blk >> 6;
    // 1024 float4 loads, 4 per thread
    for (int i = threadIdx.x; i < 1024; i += 256) {
      int ci = i >> 4, xx4 = (i & 15) * 4;
      float4 v = *(const float4*)&x[(((size_t)b * 64 + ci) * 64 + y) * 64 + xx4];
      tile[ci][xx4 + 0] = v.x;
      tile[ci][xx4 + 1] = v.y;
      tile[ci][xx4 + 2] = v.z;
      tile[ci][xx4 + 3] = v.w;
    }
    __syncthreads();
    // 1024 ushort4 stores, 4 per thread (column reads stride-65: conflict-free)
    for (int i = threadIdx.x; i < 1024; i += 256) {
      int xx = i >> 4, cip4 = (i & 15) * 4;
      ushort4 o;
      o.x = f2h(tile[cip4 + 0][xx]);
      o.y = f2h(tile[cip4 + 1][xx]);
      o.z = f2h(tile[cip4 + 2][xx]);
      o.w = f2h(tile[cip4 + 3][xx]);
      *(ushort4*)&xTp[(((size_t)(b * 64 + y) * XP) + (xx + 2)) * 64 + cip4] = o;
    }
    // zero halo cols {0,1,66,67}
    if (threadIdx.x < 128) {
      int colid = threadIdx.x >> 5;
      int col = (colid & 1) + (colid >> 1) * 66;  // 0,1,66,67
      int cip = (threadIdx.x & 31) * 2;
      ushort2 z; z.x = 0; z.y = 0;
      *(ushort2*)&xTp[(((size_t)(b * 64 + y) * XP) + col) * 64 + cip] = z;
    }
    return;
  }
  int idx = (blk - 1024) * 256 + threadIdx.x;
  if (idx < 102400) {  // w3F
    int j = idx & 7, lane = (idx >> 3) & 63, ks = (idx >> 9) & 3;
    int half = (idx >> 11) & 1, kk = idx >> 12;
    int ln = lane & 31, kh = lane >> 5;
    int co = half * 32 + ln, ci = ks * 16 + kh * 8 + j;
    w3F[idx] = f2h(w3[(co * 64 + ci) * 25 + kk]);
    return;
  }
  idx -= 102400;
  if (idx < 36864) {  // w2F
    int j = idx & 7, lane = (idx >> 3) & 63, ks = (idx >> 9) & 3;
    int half = (idx >> 11) & 1, kk = idx >> 12;
    int ln = lane & 31, kh = lane >> 5;
    int co = half * 32 + ln, ci = ks * 16 + kh * 8 + j;
    w2F[idx] = f2h(w2[(co * 64 + ci) * 9 + kk]);
    return;
  }
  idx -= 36864;
  if (idx < 36864) {  // w1F
    int j = idx & 7, lane = (idx >> 3) & 63, ks = (idx >> 9) & 3;
    int half = (idx >> 11) & 1, kk = idx >> 12;
    int ln = lane & 31, kh = lane >> 5;
    int co = half * 32 + ln, ci = ks * 16 + kh * 8 + j;
    w1F[idx] = f2h(w1[(co * 64 + ci) * 9 + kk]);
    return;
  }
  idx -= 36864;
  if (idx < 18432) {  // wofF
    int j = idx & 7, lane = (idx >> 3) & 63, ks = (idx >> 9) & 3;
    int kk = idx >> 11;
    int ln = lane & 31, kh = lane >> 5;
    int ci = ks * 16 + kh * 8 + j;
    wofF[idx] = f2h(ln < 18 ? w_off[(ln * 64 + ci) * 9 + kk] : 0.f);
  }
}

// packed fp16 bilinear blend of 4 corner f16x8 frags -> f16x8 (v_pk_fma_f16)
__device__ __forceinline__ f16x8 blend4(f16x8 va, f16x8 vb, f16x8 vc, f16x8 vd,
                                        f16x2 w00, f16x2 w01, f16x2 w10, f16x2 w11) {
  const f16x2* a = (const f16x2*)&va;
  const f16x2* b = (const f16x2*)&vb;
  const f16x2* c = (const f16x2*)&vc;
  const f16x2* d = (const f16x2*)&vd;
  f16x8 f;
  f16x2* fo = (f16x2*)&f;
#pragma unroll
  for (int i = 0; i < 4; ++i)
    fo[i] = a[i] * w00 + b[i] * w01 + c[i] * w10 + d[i] * w11;
  return f;
}

// ---------------- fused: offset conv + deform + conv5 -> s1T ----------------
// Grid (32, 16), 512 thr = 8 waves: role = wv>>2, r = (wv>>1)&1, nt = wv&1.
// role0 = offset+deform (per-ks loop), role1 = conv5.
// bx -> bxl XCD swizzle: block for y0 runs on XCD y0>>3 (matches prep writer).
__global__ __launch_bounds__(512, 4) void fused_kernel(
    const ushort* __restrict__ xTp, const ushort* __restrict__ wofF,
    const float* __restrict__ b_off, const ushort* __restrict__ w1F,
    const ushort* __restrict__ w3F,
    const float* __restrict__ g1, const float* __restrict__ b1,
    const float* __restrict__ m1, const float* __restrict__ v1,
    const float* __restrict__ g3, const float* __restrict__ b3,
    const float* __restrict__ m3, const float* __restrict__ v3,
    ushort* __restrict__ s1T) {
  __shared__ __align__(16) uint4 ldsx[6 * 68 * 8];  // 52224 B swizzled tile (exchange overlay: 32768 B)
  __shared__ float bn1s[64], bn1b[64], bn3s[64], bn3b[64];  // 1024 B

  const int tid = threadIdx.x;
  const int wv = tid >> 6, lane = tid & 63;
  const int ln = lane & 31, kh = lane >> 5;
  const int role = wv >> 2, r = (wv >> 1) & 1, nt = wv & 1;
  const int bxl = ((blockIdx.x & 7) << 2) | (blockIdx.x >> 3);  // XCD swizzle
  const int y0 = bxl * 2, b = blockIdx.y;
  const int y = y0 + r, px = nt * 32 + ln;
  const uint4* xT4 = (const uint4*)xTp;
  const ushort* xb = xTp + (size_t)b * 64 * XP * 64;
  const bool interior = (y0 >= 2 && y0 <= 60);  // block-uniform

  if (tid < 64) {
    float s = g1[tid] * rsqrtf(v1[tid] + EPSv);
    bn1s[tid] = s; bn1b[tid] = b1[tid] - m1[tid] * s;
    float s3 = g3[tid] * rsqrtf(v3[tid] + EPSv);
    bn3s[tid] = s3; bn3b[tid] = b3[tid] - m3[tid] * s3;
  }
  // stage rows y0-2..y0+3 (clamped), all 68 padded cols: no bounds branch
  for (int i = tid; i < 6 * 68 * 8; i += 512) {
    int tr = i / (68 * 8), rem = i % (68 * 8);
    int col = rem >> 3, c = rem & 7;
    int ysrc = min(max(y0 - 2 + tr, 0), 63);
    uint4 v = xT4[((size_t)((b * 64 + ysrc) * XP + col)) * 8 + c];
    ldsx[(tr * 68 + col) * 8 + (c ^ (col & 7))] = v;
  }
  __syncthreads();  // B1: tile staged

  // accKeep = my co-half output I keep (role0: deform co0-31; role1: conv5 co32-63)
  // accGive = the co-half I hand to my partner wave at the exchange.
  f32x16 accKeep, accGive;
#pragma unroll
  for (int j = 0; j < 16; ++j) { accKeep[j] = 0.f; accGive[j] = 0.f; }

  if (role == 0) {
    // ======== phase A: offset conv 3x3 from LDS (full cin) ========
    f32x16 acco;
#pragma unroll
    for (int j = 0; j < 16; ++j) acco[j] = 0.f;
    if (interior) {
#pragma unroll
      for (int kk = 0; kk < 9; ++kk) {
        const int ky = kk / 3, kx = kk % 3;
        const int tr = r + ky + 1;
        const int col = px + kx + 1;
#pragma unroll
        for (int ks = 0; ks < 4; ++ks) {
          int c = ks * 2 + kh;
          f16x8 af = *(const f16x8*)&wofF[(size_t)((kk * 4 + ks) * 64 + lane) * 8];
          f16x8 bf = *(const f16x8*)&ldsx[(tr * 68 + col) * 8 + (c ^ (col & 7))];
          acco = __builtin_amdgcn_mfma_f32_32x32x16_f16(af, bf, acco, 0, 0, 0);
        }
      }
    } else {
#pragma unroll
      for (int kk = 0; kk < 9; ++kk) {
        const int ky = kk / 3, kx = kk % 3;
        const int yy = y - 1 + ky;
        if (yy >= 0 && yy <= 63) {  // wave-uniform
          const int tr = yy - (y0 - 2);
          const int col = px + kx + 1;
#pragma unroll
          for (int ks = 0; ks < 4; ++ks) {
            int c = ks * 2 + kh;
            f16x8 af = *(const f16x8*)&wofF[(size_t)((kk * 4 + ks) * 64 + lane) * 8];
            f16x8 bf = *(const f16x8*)&ldsx[(tr * 68 + col) * 8 + (c ^ (col & 7))];
            acco = __builtin_amdgcn_mfma_f32_32x32x16_f16(af, bf, acco, 0, 0, 0);
          }
        }
      }
    }
    // offset exchange via lane^32 shuffle: co c -> reg (c&3)+4*(c>>3), src kh (c>>2)&1
    float oth[10];
#pragma unroll
    for (int t = 0; t < 10; ++t) oth[t] = __shfl_xor(acco[t], 32);
    float dyv[9], dxv[9];
#pragma unroll
    for (int kk = 0; kk < 9; ++kk) {
      const int cY = 2 * kk, cX = 2 * kk + 1;
      const int rY = (cY & 3) + 4 * (cY >> 3);
      const int rX = (cX & 3) + 4 * (cX >> 3);
      const int sY = (cY >> 2) & 1, sX = (cX >> 2) & 1;
      float vy = (sY == kh) ? acco[rY] : oth[rY];
      float vx = (sX == kh) ? acco[rX] : oth[rX];
      dyv[kk] = vy + b_off[cY];
      dxv[kk] = vx + b_off[cX];
    }
    bool fast = true;
#pragma unroll
    for (int kk = 0; kk < 9; ++kk) {
      int iy0 = (int)floorf((float)(y - 1 + kk / 3) + dyv[kk]);
      int iy1 = iy0 + 1;
      bool ok0 = (iy0 < 0) || (iy0 > 63) || (iy0 >= y0 - 2 && iy0 <= y0 + 3);
      bool ok1 = (iy1 < 0) || (iy1 > 63) || (iy1 >= y0 - 2 && iy1 <= y0 + 3);
      fast = fast && ok0 && ok1;
    }

    // ======== phase B: deformable conv 3x3 (per-ks register discipline) ========
    if (__ballot(!fast) == 0ull) {
      // branch-free fast loop (whole wave in-tile); one ks-slice live at a time
#pragma unroll
      for (int kk = 0; kk < 9; ++kk) {
        const int ky = kk / 3, kx = kk % 3;
        float ys = (float)(y - 1 + ky) + dyv[kk];
        float xs = (float)(px - 1 + kx) + dxv[kk];
        float y0f = floorf(ys), x0f = floorf(xs);
        float wy1 = ys - y0f, wx1 = xs - x0f;
        float wy0 = 1.f - wy1, wx0 = 1.f - wx1;
        int iy0 = (int)y0f, ix0 = (int)x0f;
        int iy1 = iy0 + 1, ix1 = ix0 + 1;
        float vy0 = (iy0 >= 0 && iy0 <= 63) ? 1.f : 0.f;
        float vy1 = (iy1 >= 0 && iy1 <= 63) ? 1.f : 0.f;
        float vx0 = (ix0 >= 0 && ix0 <= 63) ? 1.f : 0.f;
        float vx1 = (ix1 >= 0 && ix1 <= 63) ? 1.f : 0.f;
        int x0c = min(max(ix0, 0), 63), x1c = min(max(ix1, 0), 63);
        float w00 = wy0 * wx0 * vy0 * vx0;
        float w01 = wy0 * wx1 * vy0 * vx1;
        float w10 = wy1 * wx0 * vy1 * vx0;
        float w11 = wy1 * wx1 * vy1 * vx1;
        int tr0 = min(max(iy0 - (y0 - 2), 0), 5);
        int tr1 = min(max(iy1 - (y0 - 2), 0), 5);
        int c0 = x0c + 2, c1 = x1c + 2;
        f16x2 w00v = {(_Float16)w00, (_Float16)w00};
        f16x2 w01v = {(_Float16)w01, (_Float16)w01};
        f16x2 w10v = {(_Float16)w10, (_Float16)w10};
        f16x2 w11v = {(_Float16)w11, (_Float16)w11};
#pragma unroll
        for (int ks = 0; ks < 4; ++ks) {
          int c = ks * 2 + kh;
          f16x8 va = *(const f16x8*)&ldsx[(tr0 * 68 + c0) * 8 + (c ^ (c0 & 7))];
          f16x8 vb = *(const f16x8*)&ldsx[(tr0 * 68 + c1) * 8 + (c ^ (c1 & 7))];
          f16x8 vc = *(const f16x8*)&ldsx[(tr1 * 68 + c0) * 8 + (c ^ (c0 & 7))];
          f16x8 vd = *(const f16x8*)&ldsx[(tr1 * 68 + c1) * 8 + (c ^ (c1 & 7))];
          f16x8 f = blend4(va, vb, vc, vd, w00v, w01v, w10v, w11v);
          f16x8 a0 = *(const f16x8*)&w1F[(size_t)(((kk * 2 + 0) * 4 + ks) * 64 + lane) * 8];
          f16x8 a1 = *(const f16x8*)&w1F[(size_t)(((kk * 2 + 1) * 4 + ks) * 64 + lane) * 8];
          accKeep = __builtin_amdgcn_mfma_f32_32x32x16_f16(a0, f, accKeep, 0, 0, 0);
          accGive = __builtin_amdgcn_mfma_f32_32x32x16_f16(a1, f, accGive, 0, 0, 0);
        }
      }
    } else {
      // mixed loop (rare: some lane needs global gather); per-ks frag
#pragma unroll
      for (int kk = 0; kk < 9; ++kk) {
        const int ky = kk / 3, kx = kk % 3;
        float ys = (float)(y - 1 + ky) + dyv[kk];
        float xs = (float)(px - 1 + kx) + dxv[kk];
        float y0f = floorf(ys), x0f = floorf(xs);
        float wy1 = ys - y0f, wx1 = xs - x0f;
        float wy0 = 1.f - wy1, wx0 = 1.f - wx1;
        int iy0 = (int)y0f, ix0 = (int)x0f;
        int iy1 = iy0 + 1, ix1 = ix0 + 1;
        float vy0 = (iy0 >= 0 && iy0 <= 63) ? 1.f : 0.f;
        float vy1 = (iy1 >= 0 && iy1 <= 63) ? 1.f : 0.f;
        float vx0 = (ix0 >= 0 && ix0 <= 63) ? 1.f : 0.f;
        float vx1 = (ix1 >= 0 && ix1 <= 63) ? 1.f : 0.f;
        int x0c = min(max(ix0, 0), 63), x1c = min(max(ix1, 0), 63);
        int y0c = min(max(iy0, 0), 63), y1c = min(max(iy1, 0), 63);
        float w00 = wy0 * wx0 * vy0 * vx0;
        float w01 = wy0 * wx1 * vy0 * vx1;
        float w10 = wy1 * wx0 * vy1 * vx0;
        float w11 = wy1 * wx1 * vy1 * vx1;
        int tr0 = min(max(iy0 - (y0 - 2), 0), 5);
        int tr1 = min(max(iy1 - (y0 - 2), 0), 5);
        int c0 = x0c + 2, c1 = x1c + 2;
        f16x2 w00v = {(_Float16)w00, (_Float16)w00};
        f16x2 w01v = {(_Float16)w01, (_Float16)w01};
        f16x2 w10v = {(_Float16)w10, (_Float16)w10};
        f16x2 w11v = {(_Float16)w11, (_Float16)w11};
        const ushort* p00 = xb + ((size_t)(y0c * XP + x0c + 2)) * 64 + kh * 8;
        const ushort* p01 = xb + ((size_t)(y0c * XP + x1c + 2)) * 64 + kh * 8;
        const ushort* p10 = xb + ((size_t)(y1c * XP + x0c + 2)) * 64 + kh * 8;
        const ushort* p11 = xb + ((size_t)(y1c * XP + x1c + 2)) * 64 + kh * 8;
#pragma unroll
        for (int ks = 0; ks < 4; ++ks) {
          int c = ks * 2 + kh;
          f16x8 f;
          if (fast) {
            f16x8 va = *(const f16x8*)&ldsx[(tr0 * 68 + c0) * 8 + (c ^ (c0 & 7))];
            f16x8 vb = *(const f16x8*)&ldsx[(tr0 * 68 + c1) * 8 + (c ^ (c1 & 7))];
            f16x8 vc = *(const f16x8*)&ldsx[(tr1 * 68 + c0) * 8 + (c ^ (c0 & 7))];
            f16x8 vd = *(const f16x8*)&ldsx[(tr1 * 68 + c1) * 8 + (c ^ (c1 & 7))];
            f = blend4(va, vb, vc, vd, w00v, w01v, w10v, w11v);
          } else {
            f16x8 va = *(const f16x8*)(p00 + ks * 16);
            f16x8 vb = *(const f16x8*)(p01 + ks * 16);
            f16x8 vc = *(const f16x8*)(p10 + ks * 16);
            f16x8 vd = *(const f16x8*)(p11 + ks * 16);
            f = blend4(va, vb, vc, vd, w00v, w01v, w10v, w11v);
          }
          f16x8 a0 = *(const f16x8*)&w1F[(size_t)(((kk * 2 + 0) * 4 + ks) * 64 + lane) * 8];
          f16x8 a1 = *(const f16x8*)&w1F[(size_t)(((kk * 2 + 1) * 4 + ks) * 64 + lane) * 8];
          accKeep = __builtin_amdgcn_mfma_f32_32x32x16_f16(a0, f, accKeep, 0, 0, 0);
          accGive = __builtin_amdgcn_mfma_f32_32x32x16_f16(a1, f, accGive, 0, 0, 0);
        }
      }
    }
  } else {
    // ======== conv 5x5 from LDS (full cin) ========
    // accGive = co 0-31 (goes to role0 partner), accKeep = co 32-63
    if (interior) {
#pragma unroll
      for (int kk = 0; kk < 25; ++kk) {
        const int ky = kk / 5, kx = kk % 5;
        const int tr = r + ky;
        const int col = px + kx;
        f16x8 a0[4], a1[4], bfv[4];
#pragma unroll
        for (int ks = 0; ks < 4; ++ks) {
          a0[ks] = *(const f16x8*)&w3F[(size_t)(((kk * 2 + 0) * 4 + ks) * 64 + lane) * 8];
          a1[ks] = *(const f16x8*)&w3F[(size_t)(((kk * 2 + 1) * 4 + ks) * 64 + lane) * 8];
        }
#pragma unroll
        for (int ks = 0; ks < 4; ++ks) {
          int c = ks * 2 + kh;
          bfv[ks] = *(const f16x8*)&ldsx[(tr * 68 + col) * 8 + (c ^ (col & 7))];
        }
#pragma unroll
        for (int ks = 0; ks < 4; ++ks) {
          accGive = __builtin_amdgcn_mfma_f32_32x32x16_f16(a0[ks], bfv[ks], accGive, 0, 0, 0);
          accKeep = __builtin_amdgcn_mfma_f32_32x32x16_f16(a1[ks], bfv[ks], accKeep, 0, 0, 0);
        }
      }
    } else {
#pragma unroll
      for (int kk = 0; kk < 25; ++kk) {
        const int ky = kk / 5, kx = kk % 5;
        const int yy = y - 2 + ky;
        if (yy >= 0 && yy <= 63) {  // wave-uniform
          const int tr = r + ky;
          const int col = px + kx;
#pragma unroll
          for (int ks = 0; ks < 4; ++ks) {
            int c = ks * 2 + kh;
            f16x8 bf = *(const f16x8*)&ldsx[(tr * 68 + col) * 8 + (c ^ (col & 7))];
            f16x8 a0 = *(const f16x8*)&w3F[(size_t)(((kk * 2 + 0) * 4 + ks) * 64 + lane) * 8];
            f16x8 a1 = *(const f16x8*)&w3F[(size_t)(((kk * 2 + 1) * 4 + ks) * 64 + lane) * 8];
            accGive = __builtin_amdgcn_mfma_f32_32x32x16_f16(a0, bf, accGive, 0, 0, 0);
            accKeep = __builtin_amdgcn_mfma_f32_32x32x16_f16(a1, bf, accKeep, 0, 0, 0);
          }
        }
      }
    }
  }

  // ---------- exchange: swap co-half partials between role pair ----------
  // Slot-major overlay on ldsx: float4 sp[(pair*8 + slot)*64 + lane],
  // pair = wv&3 (role0 wave wv pairs role1 wave wv+4). 32 slots x 64
  // lanes x 16 B = 32768 B < 52224 B (bn arrays untouched). Per-slot
  // lane-consecutive float4s -> conflict-free.
  __syncthreads();  // B2 (all ldsx tile reads complete; overlay safe)
  {
    float4* sp = (float4*)ldsx;
    const int base = (wv & 3) * 8;
    union U { f32x16 v; float4 q[4]; };
    U give, got;
    give.v = accGive;
    const int wbase = base + role * 4;
#pragma unroll
    for (int j = 0; j < 4; ++j) sp[(size_t)(wbase + j) * 64 + lane] = give.q[j];
    __syncthreads();  // B3
    const int rbase = base + 4 - role * 4;
#pragma unroll
    for (int j = 0; j < 4; ++j) got.q[j] = sp[(size_t)(rbase + j) * 64 + lane];

    // role0: vd from accKeep (deform co0-31), v5 from got (conv5 co0-31)
    // role1: vd from got (deform co32-63), v5 from accKeep (conv5 co32-63)
    f32x16 vdacc = (role == 0) ? accKeep : got.v;
    f32x16 v5acc = (role == 0) ? got.v : accKeep;
    ushort* op = s1T + ((size_t)((b * 64 + y) * 64 + px)) * 64 + role * 32;
#pragma unroll
    for (int q = 0; q < 4; ++q) {
      int co0 = role * 32 + 8 * q + 4 * kh;
      float vv[4];
#pragma unroll
      for (int rr = 0; rr < 4; ++rr) {
        int co = co0 + rr;
        float vd = vdacc[q * 4 + rr] * bn1s[co] + bn1b[co];
        vd = vd > 0.f ? vd : 0.f;
        float v5 = v5acc[q * 4 + rr] * bn3s[co] + bn3b[co];
        v5 = v5 > 0.f ? v5 : 0.f;
        vv[rr] = vd + v5;
      }
      ushort4 st;
      st.x = f2h(vv[0]); st.y = f2h(vv[1]); st.z = f2h(vv[2]); st.w = f2h(vv[3]);
      *(ushort4*)(op + 8 * q + 4 * kh) = st;
    }
  }
}

// ---------------- conv3x3 on s1T + BN2 + residual + ReLU -> out ----------------
// 2-row blocks. Grid (32,16)=512, 512 thr = 8 waves (r=wv>>2,
// mh=(wv>>1)&1, nt=wv&1). Same bxl XCD swizzle as fused (reads s1T rows
// written by the same-XCD fused block).
__global__ __launch_bounds__(512, 4) void conv3_mfma_kernel(
    const ushort* __restrict__ s1T, const ushort* __restrict__ w2F,
    const float* __restrict__ g2, const float* __restrict__ b2,
    const float* __restrict__ m2, const float* __restrict__ v2,
    const float* __restrict__ x, float* __restrict__ out) {
  __shared__ __align__(16) uint4 Bt[4 * 66 * 8];  // 33792 B swizzled
  __shared__ float sc[64], bi[64];
  const int tid = threadIdx.x;
  if (tid < 64) {
    float s = g2[tid] * rsqrtf(v2[tid] + EPSv);
    sc[tid] = s;
    bi[tid] = b2[tid] - m2[tid] * s;
  }
  const int bxl = ((blockIdx.x & 7) << 2) | (blockIdx.x >> 3);  // XCD swizzle
  const int y0 = bxl * 2, b = blockIdx.y;
  const int wv = tid >> 6, lane = tid & 63;
  const int ln = lane & 31, kh = lane >> 5;
  const int r = wv >> 2, mh = (wv >> 1) & 1, nt = wv & 1;
  const int y = y0 + r;
  const int px = nt * 32 + ln;
  const uint4* s1T4 = (const uint4*)s1T;

  // stage rows y0-1..y0+2 (OOB rows zero), cols 0..65 = x cols -1..64 (OOB zero)
  for (int i = tid; i < 4 * 66 * 8; i += 512) {
    int tr = i / (66 * 8), rem = i % (66 * 8);
    int col = rem >> 3, c = rem & 7;
    int yy = y0 - 1 + tr, xcol = col - 1;
    uint4 v = make_uint4(0, 0, 0, 0);
    if (yy >= 0 && yy <= 63 && xcol >= 0 && xcol <= 63)
      v = s1T4[((size_t)((b * 64 + yy) * 64 + xcol)) * 8 + c];
    Bt[(tr * 66 + col) * 8 + (c ^ (col & 7))] = v;
  }
  __syncthreads();

  f32x16 acc;
#pragma unroll
  for (int j = 0; j < 16; ++j) acc[j] = 0.f;

#pragma unroll
  for (int kk = 0; kk < 9; ++kk) {
    const int ky = kk / 3, kx = kk % 3;
    const int col = px + kx;
    f16x8 af[4], bfr[4];
#pragma unroll
    for (int ccb = 0; ccb < 4; ++ccb)
      af[ccb] = *(const f16x8*)&w2F[(size_t)(((kk * 2 + mh) * 4 + ccb) * 64 + lane) * 8];
#pragma unroll
    for (int ccb = 0; ccb < 4; ++ccb) {
      int c = ccb * 2 + kh;
      bfr[ccb] = *(const f16x8*)&Bt[((r + ky) * 66 + col) * 8 + (c ^ (col & 7))];
    }
#pragma unroll
    for (int ccb = 0; ccb < 4; ++ccb)
      acc = __builtin_amdgcn_mfma_f32_32x32x16_f16(af[ccb], bfr[ccb], acc, 0, 0, 0);
  }
#pragma unroll
  for (int reg = 0; reg < 16; ++reg) {
    int co = (reg & 3) + 8 * (reg >> 2) + 4 * kh + mh * 32;
    size_t o = (((size_t)b * 64 + co) * 64 + y) * 64 + px;
    float v = acc[reg] * sc[co] + bi[co] + x[o];
    out[o] = v > 0.f ? v : 0.f;
  }
}

extern "C" void kernel_launch(void* const* d_in, const int* in_sizes, int n_in,
                              void* d_out, int out_size, void* d_ws, size_t ws_size,
                              hipStream_t stream) {
  const float* x     = (const float*)d_in[0];
  const float* w_off = (const float*)d_in[1];
  const float* b_off = (const float*)d_in[2];
  const float* w1    = (const float*)d_in[3];
  const float* g1    = (const float*)d_in[4];
  const float* b1    = (const float*)d_in[5];
  const float* m1    = (const float*)d_in[6];
  const float* v1    = (const float*)d_in[7];
  const float* w3    = (const float*)d_in[8];
  const float* g3    = (const float*)d_in[9];
  const float* b3    = (const float*)d_in[10];
  const float* m3    = (const float*)d_in[11];
  const float* v3    = (const float*)d_in[12];
  const float* w2    = (const float*)d_in[13];
  const float* g2    = (const float*)d_in[14];
  const float* b2    = (const float*)d_in[15];
  const float* m2    = (const float*)d_in[16];
  const float* v2    = (const float*)d_in[17];
  float* out = (float*)d_out;

  ushort* xTp  = (ushort*)d_ws;                        // 16*64*68*64 = 8.9 MB
  ushort* s1T  = xTp + (size_t)16 * 64 * XP * 64;      // 8.39 MB
  ushort* w3F  = s1T + (size_t)16 * 64 * 64 * 64;      // 102400
  ushort* w2F  = w3F + 102400;                         // 36864
  ushort* w1F  = w2F + 36864;                          // 36864
  ushort* wofF = w1F + 36864;                          // 18432

  prep_kernel<<<dim3(1024 + 760), dim3(256), 0, stream>>>(x, w3, w2, w1, w_off,
                                                          xTp, w3F, w2F, w1F, wofF);
  fused_kernel<<<dim3(32, 16), dim3(512), 0, stream>>>(xTp, wofF, b_off, w1F, w3F,
                                                       g1, b1, m1, v1, g3, b3, m3, v3,
                                                       s1T);
  conv3_mfma_kernel<<<dim3(32, 16), dim3(512), 0, stream>>>(s1T, w2F, g2, b2, m2, v2,
                                                            x, out);
}